// Round 1
// baseline (93.889 us; speedup 1.0000x reference)
//
#include <hip/hip_runtime.h>

// NURBS surface evaluation, MI355X.
// Inputs:  cp (256,256,3) f32, kvx (1,260) f32, kvy (1,260) f32
// Output:  (1,1024,1024,3) f32
//
// Kernel 1 (tiny): normalize knots (clamp<0 -> 1e-4, SEQUENTIAL cumsum to match
// numpy fp order, affine normalize), then per output coordinate compute span
// (searchsorted side='right' - 1, with u==k[256] special case), Cox-de-Boor
// basis with mod-260 wrapped knot indexing, and mod-256 control indices.
// Kernel 2: one thread per pixel, 16 gathers from the 768KB (L2-resident)
// control-point table, 4x4 weighted blend, contiguous 12B/thread store.

#define KLEN  260   // knot vector length = N_CTRL + DEGREE + 1
#define NCTRL 256
#define OUTN  1024
#define DEG   3
#define EPSV  1e-5

__global__ __launch_bounds__(256) void nurbs_prep(
    const float* __restrict__ kvx, const float* __restrict__ kvy,
    float4* __restrict__ bx4, int4* __restrict__ ix4,
    float4* __restrict__ by4, int4* __restrict__ iy4) {
  __shared__ float kn[2][KLEN];
  const int t = threadIdx.x;

  for (int i = t; i < KLEN; i += 256) {
    kn[0][i] = kvx[i];
    kn[1][i] = kvy[i];
  }
  __syncthreads();

  // Sequential cumsum + normalize, one knot vector per lane (lanes 0,1).
  // Serial on purpose: fp add order must match numpy's cumsum.
  if (t < 2) {
    float* a = kn[t];
    float run = 0.f;
    #pragma unroll 4
    for (int i = 0; i < KLEN; ++i) {
      float v = a[i];
      v = (v < 0.f) ? 1e-4f : v;
      run += v;
      a[i] = run;
    }
    const float c0 = a[0];
    const float d  = a[KLEN - 1] - c0;
    #pragma unroll 4
    for (int i = 0; i < KLEN; ++i) a[i] = (a[i] - c0) / d;
  }
  __syncthreads();

  // linspace step in double to match numpy's internal f64 linspace, cast at use.
  const double step = (1.0 - 2.0 * (double)EPSV) / (double)(OUTN - 1);

  for (int item = t; item < 2 * OUTN; item += 256) {
    const int which = item >> 10;      // 0 = x axis, 1 = y axis
    const int idx   = item & (OUTN - 1);
    const float* k  = kn[which];
    const float u   = (float)((double)EPSV + (double)idx * step);

    // searchsorted(k, u, side='right') - 1  == upper_bound - 1
    int lo = 0, hi = KLEN;
    while (lo < hi) {
      int mid = (lo + hi) >> 1;
      if (k[mid] <= u) lo = mid + 1; else hi = mid;
    }
    int span = lo - 1;
    if (u == k[NCTRL]) span = NCTRL - 1;

    // Cox-de-Boor with mod-KLEN wrapped knot indexing (matches reference).
    float left[DEG + 1], right[DEG + 1], cols[DEG + 1];
    cols[0] = 1.f;
    #pragma unroll
    for (int j = 1; j <= DEG; ++j) {
      int li = span + 1 - j; li %= KLEN; if (li < 0) li += KLEN;
      int ri = (span + j) % KLEN;
      left[j]  = u - k[li];
      right[j] = k[ri] - u;
      float saved = 0.f;
      #pragma unroll
      for (int r = 0; r < j; ++r) {
        float temp = cols[r] / (right[r + 1] + left[j - r]);
        cols[r] = saved + right[r + 1] * temp;
        saved = left[j - r] * temp;
      }
      cols[j] = saved;
    }

    float4 b; b.x = cols[0]; b.y = cols[1]; b.z = cols[2]; b.w = cols[3];
    int4 ii;
    ii.x = (span - DEG + 0) & (NCTRL - 1);   // & works: two's-complement mod-256
    ii.y = (span - DEG + 1) & (NCTRL - 1);
    ii.z = (span - DEG + 2) & (NCTRL - 1);
    ii.w = (span - DEG + 3) & (NCTRL - 1);

    if (which == 0) { bx4[idx] = b; ix4[idx] = ii; }
    else            { by4[idx] = b; iy4[idx] = ii; }
  }
}

__global__ __launch_bounds__(256) void nurbs_eval(
    const float* __restrict__ cp,
    const float4* __restrict__ bx4, const int4* __restrict__ ix4,
    const float4* __restrict__ by4, const int4* __restrict__ iy4,
    float* __restrict__ out) {
  const int f = (blockIdx.x << 8) + threadIdx.x;  // fast axis: coalesced
  const int e = blockIdx.y;                       // wave-uniform -> scalar loads

  const float4 wx = bx4[e];
  const int4   rx = ix4[e];
  const float4 wy = by4[f];
  const int4   ry = iy4[f];

  const float wl[4] = {wx.x, wx.y, wx.z, wx.w};
  const int   il[4] = {rx.x * (NCTRL * 3), rx.y * (NCTRL * 3),
                       rx.z * (NCTRL * 3), rx.w * (NCTRL * 3)};
  const float wr[4] = {wy.x, wy.y, wy.z, wy.w};
  const int   ir[4] = {ry.x * 3, ry.y * 3, ry.z * 3, ry.w * 3};

  float ax = 0.f, ay = 0.f, az = 0.f;
  #pragma unroll
  for (int l = 0; l < 4; ++l) {
    const float* rowp = cp + il[l];
    const float wlv = wl[l];
    #pragma unroll
    for (int r = 0; r < 4; ++r) {
      const float w = wlv * wr[r];
      const float* p = rowp + ir[r];
      ax += w * p[0];
      ay += w * p[1];
      az += w * p[2];
    }
  }

  const int o = ((e << 10) + f) * 3;
  out[o + 0] = ax;
  out[o + 1] = ay;
  out[o + 2] = az;
}

extern "C" void kernel_launch(void* const* d_in, const int* in_sizes, int n_in,
                              void* d_out, int out_size, void* d_ws, size_t ws_size,
                              hipStream_t stream) {
  (void)in_sizes; (void)n_in; (void)out_size; (void)ws_size;
  const float* cp  = (const float*)d_in[0];
  const float* kvx = (const float*)d_in[1];
  const float* kvy = (const float*)d_in[2];
  float* out = (float*)d_out;

  char* ws = (char*)d_ws;
  float4* bx4 = (float4*)(ws);            // 1024 * 16 B
  int4*   ix4 = (int4*)  (ws + 16384);    // 1024 * 16 B
  float4* by4 = (float4*)(ws + 32768);    // 1024 * 16 B
  int4*   iy4 = (int4*)  (ws + 49152);    // 1024 * 16 B

  nurbs_prep<<<1, 256, 0, stream>>>(kvx, kvy, bx4, ix4, by4, iy4);
  nurbs_eval<<<dim3(4, 1024), 256, 0, stream>>>(cp, bx4, ix4, by4, iy4, out);
}